// Round 4
// baseline (21166.446 us; speedup 1.0000x reference)
//
#include <hip/hip_runtime.h>
#include <hip/hip_bf16.h>
#include <math.h>

typedef __bf16 bf16;
typedef __bf16 bf16x8 __attribute__((ext_vector_type(8)));
typedef float  f32x4  __attribute__((ext_vector_type(4)));

#define MFMA16(a, b, c) __builtin_amdgcn_mfma_f32_16x16x32_bf16((a), (b), (c), 0, 0, 0)

// Problem constants
#define BB 64
#define TT 512
#define HH 512
#define G4 2048      // 4*HH gate rows, permuted row' = 4*u + g
#define NROW 32768   // BB*TT, row index r = t*64 + b
#define K2 1024      // dedup 2-plane width: weights [hi|lo], activations [hh|hl]
#define K3 1536      // logical triple K for gemm_out (A = [hi|hi|lo], B mapped)
#define NWG 256

__device__ __forceinline__ float sigmoidf_(float x) { return 1.0f / (1.0f + expf(-x)); }

// ---------------------------------------------------------------------------
// Padded byte stream: bytes[b][p], p in [0,520): 7x NULL, SOS, payload
// ---------------------------------------------------------------------------
__global__ void pad_bytes(const int* __restrict__ payload, int* __restrict__ bytes) {
    int b = blockIdx.x;
    for (int p = threadIdx.x; p < 520; p += blockDim.x)
        bytes[b * 520 + p] = (p < 7) ? 256 : ((p == 7) ? 257 : payload[b * 512 + p - 8]);
}

// ---------------------------------------------------------------------------
// Z[v][j][m'] = sum_kk Wih0[orig(m')][792 + j*32 + kk] * bemb[v][kk]   (fp32 exact)
// ---------------------------------------------------------------------------
__global__ void build_Z(const float* __restrict__ Wih0, const float* __restrict__ bemb,
                        float* __restrict__ Z) {
    int v = blockIdx.x, j = blockIdx.y;
    __shared__ float e[32];
    if (threadIdx.x < 32) e[threadIdx.x] = bemb[v * 32 + threadIdx.x];
    __syncthreads();
#pragma unroll
    for (int i = 0; i < 8; i++) {
        int mp = threadIdx.x + i * 256;
        int u = mp >> 2, g = mp & 3;
        const float* wr = Wih0 + (size_t)(g * 512 + u) * 1048 + 792 + j * 32;
        float sum = 0.f;
#pragma unroll
        for (int kk = 0; kk < 32; kk++) sum += wr[kk] * e[kk];
        Z[((size_t)(v * 8 + j)) * G4 + mp] = sum;
    }
}

// ---------------------------------------------------------------------------
// ctx_gates[b][m'] = Wih0[orig(m')][0:792] . context[b] + bih0 + bhh0  (fp32 exact)
// ---------------------------------------------------------------------------
__global__ void build_ctxg(const float* __restrict__ ecc, const int* __restrict__ npc,
                           const float* __restrict__ npn,
                           const float* __restrict__ cat0, const float* __restrict__ cat1,
                           const float* __restrict__ cat2,
                           const float* __restrict__ bih0, const float* __restrict__ bhh0,
                           const float* __restrict__ Wih0, float* __restrict__ ctxg) {
    int b = blockIdx.x;
    __shared__ float cs[792];
    for (int k = threadIdx.x; k < 792; k += blockDim.x) {
        float v;
        if (k < 512)       v = ecc[b * 512 + k];
        else if (k < 562)  v = cat0[npc[b * 3 + 0] * 50 + (k - 512)];
        else if (k < 626)  v = cat1[npc[b * 3 + 1] * 64 + (k - 562)];
        else if (k < 776)  v = cat2[npc[b * 3 + 2] * 150 + (k - 626)];
        else               v = npn[b * 16 + (k - 776)];
        cs[k] = v;
    }
    __syncthreads();
#pragma unroll
    for (int i = 0; i < 8; i++) {
        int mp = threadIdx.x + i * 256;
        int u = mp >> 2, g = mp & 3;
        int orow = g * 512 + u;
        const float* wr = Wih0 + (size_t)orow * 1048;
        float sum = bih0[orow] + bhh0[orow];
        for (int k = 0; k < 792; k++) sum += wr[k] * cs[k];
        ctxg[b * G4 + mp] = sum;
    }
}

// ---------------------------------------------------------------------------
// Weight conversions, dedup 2-plane [hi | lo], row stride K2 (or 2*K2 for W1).
// ---------------------------------------------------------------------------
__global__ void conv_w0(const float* __restrict__ Whh0, bf16* __restrict__ W0p) {
    int rp = blockIdx.x; int u = rp >> 2, g = rp & 3;
    const float* src = Whh0 + (size_t)(g * 512 + u) * 512;
    bf16* dst = W0p + (size_t)rp * K2;
    for (int k = threadIdx.x; k < 512; k += blockDim.x) {
        float w = src[k]; bf16 hi = (bf16)w; bf16 lo = (bf16)(w - (float)hi);
        dst[k] = hi; dst[512 + k] = lo;
    }
}
__global__ void conv_w1(const float* __restrict__ Wih1, const float* __restrict__ Whh1,
                        bf16* __restrict__ W1p) {
    int rp = blockIdx.x; int u = rp >> 2, g = rp & 3;
    const float* s0 = Wih1 + (size_t)(g * 512 + u) * 512;
    const float* s1 = Whh1 + (size_t)(g * 512 + u) * 512;
    bf16* dst = W1p + (size_t)rp * (2 * K2);
    for (int k = threadIdx.x; k < 512; k += blockDim.x) {
        float w0 = s0[k]; bf16 h0 = (bf16)w0; bf16 l0 = (bf16)(w0 - (float)h0);
        dst[k] = h0; dst[512 + k] = l0;
        float w1 = s1[k]; bf16 h1 = (bf16)w1; bf16 l1 = (bf16)(w1 - (float)h1);
        dst[1024 + k] = h1; dst[1536 + k] = l1;
    }
}
__global__ void conv_wout(const float* __restrict__ Wout, bf16* __restrict__ Woutp) {
    int r = blockIdx.x;
    const float* src = Wout + (size_t)r * 512;
    bf16* dst = Woutp + (size_t)r * K3;            // triple [hi|hi|lo]
    for (int k = threadIdx.x; k < 512; k += blockDim.x) {
        float w = src[k]; bf16 hi = (bf16)w; bf16 lo = (bf16)(w - (float)hi);
        dst[k] = hi; dst[512 + k] = hi; dst[1024 + k] = lo;
    }
}
__global__ void conv_bias(const float* __restrict__ bih1, const float* __restrict__ bhh1,
                          float* __restrict__ bias1p) {
    int rp = blockIdx.x * blockDim.x + threadIdx.x;
    if (rp >= G4) return;
    int u = rp >> 2, g = rp & 3; int orow = g * 512 + u;
    bias1p[rp] = bih1[orow] + bhh1[orow];
}

// ---------------------------------------------------------------------------
// Grid barrier for a 256-wg persistent kernel (regular launch; co-residency
// guaranteed: 0 LDS, <=512 VGPR => >=1 block/CU, grid == CU count).
// Release: one __threadfence (XCD-L2 writeback) + relaxed agent store.
// Poll: relaxed agent loads (read through to coherence point; no inv spam).
// Acquire: __threadfence after observation (invalidate L1/L2 before h reads).
// slots[] zeroed每 call; counter monotonic within the call.
// ---------------------------------------------------------------------------
__device__ __forceinline__ void grid_barrier(unsigned* slots, int w, int tid, unsigned s1) {
    __syncthreads();   // all waves' h stores drained to L2 before release
    if (tid == 0) {
        __threadfence();
        __hip_atomic_store(&slots[w], s1, __ATOMIC_RELAXED, __HIP_MEMORY_SCOPE_AGENT);
    }
    while (__hip_atomic_load(&slots[tid], __ATOMIC_RELAXED, __HIP_MEMORY_SCOPE_AGENT) < s1)
        __builtin_amdgcn_s_sleep(1);
    __syncthreads();
    __threadfence();
}

// ---------------------------------------------------------------------------
// Persistent LSTM kernel. 256 wgs.
//   wg < 128: layer0 row-tile rt=wg     (steps t = s)
//   wg >=128: layer1 row-tile rt=wg-128 (steps t = s-1)
// Weights live in VGPRs (loaded once). h buffers 2-plane [hh|hl], stride K2.
// ---------------------------------------------------------------------------
__global__ __launch_bounds__(256, 1) void lstm_persist(
        const bf16* __restrict__ W0p, const bf16* __restrict__ W1p,
        const float* __restrict__ bias1p, const float* __restrict__ ctxg,
        const float* __restrict__ Z, const int* __restrict__ bytes,
        bf16* __restrict__ h0a, bf16* __restrict__ h0b,
        bf16* __restrict__ h1a, bf16* __restrict__ h1b,
        bf16* __restrict__ h2all, unsigned* __restrict__ slots) {
    int w = blockIdx.x, tid = threadIdx.x;
    int bt = tid >> 6, lane = tid & 63, l15 = lane & 15, q = lane >> 4;
    int b = bt * 16 + l15;

    if (w < 128) {                       // ================= layer 0
        int rt = w;
        int u = rt * 4 + q;
        bf16x8 A[16][2];
        {
            const bf16* Ab = W0p + (size_t)(rt * 16 + l15) * K2 + q * 8;
#pragma unroll
            for (int ks = 0; ks < 16; ks++) {
                A[ks][0] = *(const bf16x8*)(Ab + ks * 32);
                A[ks][1] = *(const bf16x8*)(Ab + 512 + ks * 32);
            }
        }
        f32x4 ctxgv = *(const f32x4*)&ctxg[b * G4 + rt * 16 + q * 4];
        const int* bp0 = bytes + b * 520;
        float c = 0.f;
        for (int s = 0; s <= TT; s++) {
            if (s < TT) {
                int t = s;
                int vt[8];
#pragma unroll
                for (int j = 0; j < 8; j++) vt[j] = bp0[t + j];
                f32x4 zv[8];
#pragma unroll
                for (int j = 0; j < 8; j++)
                    zv[j] = *(const f32x4*)&Z[((size_t)((vt[j] << 3) + j)) * G4 + rt * 16 + q * 4];
                const bf16* Br = ((s & 1) ? h0a : h0b) + (size_t)b * K2 + q * 8;
                f32x4 a0 = {0.f,0.f,0.f,0.f}, a1 = a0, a2 = a0;
#pragma unroll
                for (int ks = 0; ks < 16; ks++) {
                    bf16x8 bhh = *(const bf16x8*)(Br + ks * 32);
                    bf16x8 bhl = *(const bf16x8*)(Br + 512 + ks * 32);
                    a0 = MFMA16(A[ks][0], bhh, a0);
                    a1 = MFMA16(A[ks][0], bhl, a1);
                    a2 = MFMA16(A[ks][1], bhh, a2);
                }
                f32x4 g = ctxgv;
#pragma unroll
                for (int j = 0; j < 8; j++) g += zv[j];
                f32x4 acc = a0 + a1 + a2;
                float gi = acc[0] + g[0], gf = acc[1] + g[1], gg = acc[2] + g[2], go = acc[3] + g[3];
                float cnew = sigmoidf_(gf) * c + sigmoidf_(gi) * tanhf(gg);
                c = cnew;
                float h = sigmoidf_(go) * tanhf(cnew);
                bf16 hh = (bf16)h; bf16 hl = (bf16)(h - (float)hh);
                bf16* hw = ((s & 1) ? h0b : h0a) + (size_t)b * K2;
                hw[u] = hh; hw[512 + u] = hl;
            }
            if (s < TT) grid_barrier(slots, w, tid, (unsigned)(s + 1));
        }
    } else {                             // ================= layer 1
        int rt = w - 128;
        int u = rt * 4 + q;
        bf16x8 A[2][16][2];
        {
            const bf16* Ab = W1p + (size_t)(rt * 16 + l15) * (2 * K2) + q * 8;
#pragma unroll
            for (int m = 0; m < 2; m++)
#pragma unroll
                for (int ks = 0; ks < 16; ks++) {
                    A[m][ks][0] = *(const bf16x8*)(Ab + m * 1024 + ks * 32);
                    A[m][ks][1] = *(const bf16x8*)(Ab + m * 1024 + 512 + ks * 32);
                }
        }
        f32x4 bi = *(const f32x4*)&bias1p[rt * 16 + q * 4];
        float c = 0.f;
        for (int s = 0; s <= TT; s++) {
            if (s >= 1) {
                int t = s - 1;
                const bf16* B0 = ((s & 1) ? h0a : h0b) + (size_t)b * K2 + q * 8;  // h0_t
                const bf16* B1 = ((s & 1) ? h1a : h1b) + (size_t)b * K2 + q * 8;  // h1_{t-1}
                f32x4 a0 = {0.f,0.f,0.f,0.f}, a1 = a0, a2 = a0;
#pragma unroll
                for (int ks = 0; ks < 16; ks++) {
                    bf16x8 b0h = *(const bf16x8*)(B0 + ks * 32);
                    bf16x8 b0l = *(const bf16x8*)(B0 + 512 + ks * 32);
                    bf16x8 b1h = *(const bf16x8*)(B1 + ks * 32);
                    bf16x8 b1l = *(const bf16x8*)(B1 + 512 + ks * 32);
                    a0 = MFMA16(A[0][ks][0], b0h, a0);
                    a1 = MFMA16(A[0][ks][0], b0l, a1);
                    a2 = MFMA16(A[0][ks][1], b0h, a2);
                    a0 = MFMA16(A[1][ks][0], b1h, a0);
                    a1 = MFMA16(A[1][ks][0], b1l, a1);
                    a2 = MFMA16(A[1][ks][1], b1h, a2);
                }
                f32x4 acc = a0 + a1 + a2;
                float gi = acc[0] + bi[0], gf = acc[1] + bi[1], gg = acc[2] + bi[2], go = acc[3] + bi[3];
                float cnew = sigmoidf_(gf) * c + sigmoidf_(gi) * tanhf(gg);
                c = cnew;
                float h = sigmoidf_(go) * tanhf(cnew);
                bf16 hh = (bf16)h; bf16 hl = (bf16)(h - (float)hh);
                bf16* hw = ((s & 1) ? h1b : h1a) + (size_t)b * K2;
                hw[u] = hh; hw[512 + u] = hl;
                bf16* h2 = h2all + ((size_t)(t * 64 + b)) * K2;
                h2[u] = hh; h2[512 + u] = hl;
            }
            if (s < TT) grid_barrier(slots, w, tid, (unsigned)(s + 1));
        }
    }
}

// ---------------------------------------------------------------------------
// Phase C: logits[b,t,v] = Woutp[v][0:1536] . h2trip + bout[v]
// A is triple (K3); B stored 2-plane (K2) with column map k>=1024 -> k-1024.
// ---------------------------------------------------------------------------
__global__ __launch_bounds__(256, 2) void gemm_out(const bf16* __restrict__ Wp,
                                                   const bf16* __restrict__ H2,
                                                   const float* __restrict__ bout,
                                                   float* __restrict__ out) {
    __shared__ bf16 As[128 * 32];
    __shared__ bf16 Bs[128 * 32];
    int mt = blockIdx.x, nt = blockIdx.y;
    int tid = threadIdx.x, wave = tid >> 6, lane = tid & 63;
    int l15 = lane & 15, q = lane >> 4;
    int msub = (wave & 1) * 64, nsub = (wave >> 1) * 64;
    f32x4 acc[4][4] = {};
    const bf16* Abase = Wp + (size_t)(mt * 128) * K3;
    const bf16* Bbase = H2 + (size_t)(nt * 128) * K2;
    for (int ks = 0; ks < K3 / 32; ks++) {
        int k0 = ks * 32;
        int kb = (k0 < 1024) ? k0 : (k0 - 1024);
        __syncthreads();
#pragma unroll
        for (int rnd = 0; rnd < 2; rnd++) {
            int cch = tid + rnd * 256;
            int rr = cch >> 2, seg = cch & 3;
            *(int4*)&As[cch * 8] = *(const int4*)&Abase[(size_t)rr * K3 + k0 + seg * 8];
            *(int4*)&Bs[cch * 8] = *(const int4*)&Bbase[(size_t)rr * K2 + kb + seg * 8];
        }
        __syncthreads();
        bf16x8 af[4], bf_[4];
#pragma unroll
        for (int i = 0; i < 4; i++) af[i]  = *(const bf16x8*)&As[(msub + i * 16 + l15) * 32 + q * 8];
#pragma unroll
        for (int j = 0; j < 4; j++) bf_[j] = *(const bf16x8*)&Bs[(nsub + j * 16 + l15) * 32 + q * 8];
#pragma unroll
        for (int i = 0; i < 4; i++)
#pragma unroll
            for (int j = 0; j < 4; j++)
                acc[i][j] = MFMA16(af[i], bf_[j], acc[i][j]);
    }
#pragma unroll
    for (int i = 0; i < 4; i++) {
        int m = mt * 128 + msub + i * 16 + q * 4;     // vocab row
        f32x4 bi = *(const f32x4*)&bout[m];
#pragma unroll
        for (int j = 0; j < 4; j++) {
            int n = nt * 128 + nsub + j * 16 + l15;   // t*64+b
            int t = n >> 6, b = n & 63;
            f32x4 v = acc[i][j] + bi;
            *(f32x4*)&out[((size_t)(b * 512 + t)) * 256 + m] = v;
        }
    }
}

// ---------------------------------------------------------------------------
extern "C" void kernel_launch(void* const* d_in, const int* in_sizes, int n_in,
                              void* d_out, int out_size, void* d_ws, size_t ws_size,
                              hipStream_t stream) {
    const float* ecc   = (const float*)d_in[0];
    const int*   npc   = (const int*)d_in[1];
    const float* npn   = (const float*)d_in[2];
    const int*   payld = (const int*)d_in[3];
    const float* cat0  = (const float*)d_in[4];
    const float* cat1  = (const float*)d_in[5];
    const float* cat2  = (const float*)d_in[6];
    const float* bemb  = (const float*)d_in[7];
    const float* Wih0  = (const float*)d_in[8];
    const float* Whh0  = (const float*)d_in[9];
    const float* bih0  = (const float*)d_in[10];
    const float* bhh0  = (const float*)d_in[11];
    const float* Wih1  = (const float*)d_in[12];
    const float* Whh1  = (const float*)d_in[13];
    const float* bih1  = (const float*)d_in[14];
    const float* bhh1  = (const float*)d_in[15];
    const float* Wout  = (const float*)d_in[16];
    const float* bout  = (const float*)d_in[17];
    float* out = (float*)d_out;

    char* ws = (char*)d_ws;
    size_t off = 0;
    auto alloc = [&](size_t bytes) -> void* {
        void* p = ws + off;
        off = (off + bytes + 255) & ~(size_t)255;
        return p;
    };

    // zeroed state block (contiguous)
    size_t zoff = off;
    bf16* h0a = (bf16*)alloc((size_t)BB * K2 * 2);
    bf16* h0b = (bf16*)alloc((size_t)BB * K2 * 2);
    bf16* h1a = (bf16*)alloc((size_t)BB * K2 * 2);
    bf16* h1b = (bf16*)alloc((size_t)BB * K2 * 2);
    unsigned* slots = (unsigned*)alloc(NWG * 4);
    size_t zbytes = off - zoff;

    bf16* W0p    = (bf16*)alloc((size_t)G4 * K2 * 2);
    bf16* W1p    = (bf16*)alloc((size_t)G4 * 2 * K2 * 2);
    bf16* Woutp  = (bf16*)alloc((size_t)256 * K3 * 2);
    float* bias1p = (float*)alloc((size_t)G4 * 4);
    float* Z      = (float*)alloc((size_t)260 * 8 * G4 * 4);
    float* ctxg   = (float*)alloc((size_t)BB * G4 * 4);
    int*   bytesb = (int*)alloc((size_t)BB * 520 * 4);
    bf16* h2all   = (bf16*)alloc((size_t)NROW * K2 * 2);

    if (ws_size < off) return;   // out stays poisoned -> signals ws too small

    hipMemsetAsync(ws + zoff, 0, zbytes, stream);

    pad_bytes <<<BB, 256, 0, stream>>>(payld, bytesb);
    build_Z   <<<dim3(260, 8), 256, 0, stream>>>(Wih0, bemb, Z);
    build_ctxg<<<BB, 256, 0, stream>>>(ecc, npc, npn, cat0, cat1, cat2, bih0, bhh0, Wih0, ctxg);
    conv_w0   <<<G4, 256, 0, stream>>>(Whh0, W0p);
    conv_w1   <<<G4, 256, 0, stream>>>(Wih1, Whh1, W1p);
    conv_wout <<<256, 256, 0, stream>>>(Wout, Woutp);
    conv_bias <<<8, 256, 0, stream>>>(bih1, bhh1, bias1p);

    lstm_persist<<<NWG, 256, 0, stream>>>(W0p, W1p, bias1p, ctxg, Z, bytesb,
                                          h0a, h0b, h1a, h1b, h2all, slots);

    gemm_out<<<dim3(2, 256), 256, 0, stream>>>(Woutp, h2all, bout, out);
}

// Round 5
// 6878.230 us; speedup vs baseline: 3.0773x; 3.0773x over previous
//
#include <hip/hip_runtime.h>
#include <hip/hip_bf16.h>
#include <math.h>

typedef __bf16 bf16;
typedef __bf16 bf16x8 __attribute__((ext_vector_type(8)));
typedef float  f32x4  __attribute__((ext_vector_type(4)));
typedef unsigned long long u64;

#define MFMA16(a, b, c) __builtin_amdgcn_mfma_f32_16x16x32_bf16((a), (b), (c), 0, 0, 0)

// Problem constants
#define BB 64
#define TT 512
#define HH 512
#define G4 2048      // 4*HH gate rows, permuted row' = 4*u + g
#define NROW 32768   // BB*TT, row index r = t*64 + b
#define K2 1024      // dedup 2-plane width: [hi|lo] weights, [hh|hl] activations
#define K3 1536      // logical triple K for gemm_out (A = [hi|hi|lo], B mapped)
#define NWG 256
#define LROW 1048    // LDS slab row stride in bf16 elements (1024 + 24 pad)

__device__ __forceinline__ float sigmoidf_(float x) { return 1.0f / (1.0f + expf(-x)); }

// pack h into {hh, hl} bf16 pair in one u32
__device__ __forceinline__ unsigned pack32(float h) {
    bf16 hh = (bf16)h;
    bf16 hl = (bf16)(h - (float)hh);
    unsigned short uh = __builtin_bit_cast(unsigned short, hh);
    unsigned short ul = __builtin_bit_cast(unsigned short, hl);
    return (unsigned)uh | ((unsigned)ul << 16);
}

// ---------------------------------------------------------------------------
// Setup kernels (unchanged from round 4)
// ---------------------------------------------------------------------------
__global__ void pad_bytes(const int* __restrict__ payload, int* __restrict__ bytes) {
    int b = blockIdx.x;
    for (int p = threadIdx.x; p < 520; p += blockDim.x)
        bytes[b * 520 + p] = (p < 7) ? 256 : ((p == 7) ? 257 : payload[b * 512 + p - 8]);
}

__global__ void build_Z(const float* __restrict__ Wih0, const float* __restrict__ bemb,
                        float* __restrict__ Z) {
    int v = blockIdx.x, j = blockIdx.y;
    __shared__ float e[32];
    if (threadIdx.x < 32) e[threadIdx.x] = bemb[v * 32 + threadIdx.x];
    __syncthreads();
#pragma unroll
    for (int i = 0; i < 8; i++) {
        int mp = threadIdx.x + i * 256;
        int u = mp >> 2, g = mp & 3;
        const float* wr = Wih0 + (size_t)(g * 512 + u) * 1048 + 792 + j * 32;
        float sum = 0.f;
#pragma unroll
        for (int kk = 0; kk < 32; kk++) sum += wr[kk] * e[kk];
        Z[((size_t)(v * 8 + j)) * G4 + mp] = sum;
    }
}

__global__ void build_ctxg(const float* __restrict__ ecc, const int* __restrict__ npc,
                           const float* __restrict__ npn,
                           const float* __restrict__ cat0, const float* __restrict__ cat1,
                           const float* __restrict__ cat2,
                           const float* __restrict__ bih0, const float* __restrict__ bhh0,
                           const float* __restrict__ Wih0, float* __restrict__ ctxg) {
    int b = blockIdx.x;
    __shared__ float cs[792];
    for (int k = threadIdx.x; k < 792; k += blockDim.x) {
        float v;
        if (k < 512)       v = ecc[b * 512 + k];
        else if (k < 562)  v = cat0[npc[b * 3 + 0] * 50 + (k - 512)];
        else if (k < 626)  v = cat1[npc[b * 3 + 1] * 64 + (k - 562)];
        else if (k < 776)  v = cat2[npc[b * 3 + 2] * 150 + (k - 626)];
        else               v = npn[b * 16 + (k - 776)];
        cs[k] = v;
    }
    __syncthreads();
#pragma unroll
    for (int i = 0; i < 8; i++) {
        int mp = threadIdx.x + i * 256;
        int u = mp >> 2, g = mp & 3;
        int orow = g * 512 + u;
        const float* wr = Wih0 + (size_t)orow * 1048;
        float sum = bih0[orow] + bhh0[orow];
        for (int k = 0; k < 792; k++) sum += wr[k] * cs[k];
        ctxg[b * G4 + mp] = sum;
    }
}

__global__ void conv_w0(const float* __restrict__ Whh0, bf16* __restrict__ W0p) {
    int rp = blockIdx.x; int u = rp >> 2, g = rp & 3;
    const float* src = Whh0 + (size_t)(g * 512 + u) * 512;
    bf16* dst = W0p + (size_t)rp * K2;
    for (int k = threadIdx.x; k < 512; k += blockDim.x) {
        float w = src[k]; bf16 hi = (bf16)w; bf16 lo = (bf16)(w - (float)hi);
        dst[k] = hi; dst[512 + k] = lo;
    }
}
__global__ void conv_w1(const float* __restrict__ Wih1, const float* __restrict__ Whh1,
                        bf16* __restrict__ W1p) {
    int rp = blockIdx.x; int u = rp >> 2, g = rp & 3;
    const float* s0 = Wih1 + (size_t)(g * 512 + u) * 512;
    const float* s1 = Whh1 + (size_t)(g * 512 + u) * 512;
    bf16* dst = W1p + (size_t)rp * (2 * K2);
    for (int k = threadIdx.x; k < 512; k += blockDim.x) {
        float w0 = s0[k]; bf16 h0 = (bf16)w0; bf16 l0 = (bf16)(w0 - (float)h0);
        dst[k] = h0; dst[512 + k] = l0;
        float w1 = s1[k]; bf16 h1 = (bf16)w1; bf16 l1 = (bf16)(w1 - (float)h1);
        dst[1024 + k] = h1; dst[1536 + k] = l1;
    }
}
__global__ void conv_wout(const float* __restrict__ Wout, bf16* __restrict__ Woutp) {
    int r = blockIdx.x;
    const float* src = Wout + (size_t)r * 512;
    bf16* dst = Woutp + (size_t)r * K3;            // triple [hi|hi|lo]
    for (int k = threadIdx.x; k < 512; k += blockDim.x) {
        float w = src[k]; bf16 hi = (bf16)w; bf16 lo = (bf16)(w - (float)hi);
        dst[k] = hi; dst[512 + k] = hi; dst[1024 + k] = lo;
    }
}
__global__ void conv_bias(const float* __restrict__ bih1, const float* __restrict__ bhh1,
                          float* __restrict__ bias1p) {
    int rp = blockIdx.x * blockDim.x + threadIdx.x;
    if (rp >= G4) return;
    int u = rp >> 2, g = rp & 3; int orow = g * 512 + u;
    bias1p[rp] = bih1[orow] + bhh1[orow];
}

// ---------------------------------------------------------------------------
// Fence-light grid barrier: NO L2 invalidate/writeback anywhere.
// h is exchanged via agent-scope relaxed atomics (write-through/read-through),
// so visibility needs only vmcnt drain (done by syncthreads) + slot atomics.
// __threadfence_block = s_waitcnt only (compiler ordering, no cache ops).
// ---------------------------------------------------------------------------
__device__ __forceinline__ void grid_barrier(unsigned* slots, int w, int tid, unsigned s1) {
    __syncthreads();                 // all waves' atomic h stores vmcnt-drained
    __threadfence_block();
    if (tid == 0)
        __hip_atomic_store(&slots[w], s1, __ATOMIC_RELAXED, __HIP_MEMORY_SCOPE_AGENT);
    while (__hip_atomic_load(&slots[tid], __ATOMIC_RELAXED, __HIP_MEMORY_SCOPE_AGENT) < s1)
        __builtin_amdgcn_s_sleep(2);
    __threadfence_block();
    __syncthreads();
}

// ---------------------------------------------------------------------------
// Persistent LSTM. 256 wgs, 1/CU guaranteed (67KB LDS, 256 thr).
//  wg w<128: layer0, mg = w>>2 (rows mg*64..+64), bg = w&3 (batches bg*16..+16)
//  wg w>=128: layer1, same decomposition.
// Waves split M (16 rows = 1 m-tile each); wg covers 16 batches -> h slab
// staged once per wg into LDS via 8B read-through atomic loads.
// Lane (l15,q) of wave wv owns all 4 gates of (b=bg*16+l15, u=mg*16+wv*4+q);
// c-state in a register. h written as packed 8B agent atomics (2 planes).
// ---------------------------------------------------------------------------
__global__ __launch_bounds__(256, 1) void lstm_persist(
        const bf16* __restrict__ W0p, const bf16* __restrict__ W1p,
        const float* __restrict__ bias1p, const float* __restrict__ ctxg,
        const float* __restrict__ Z, const int* __restrict__ bytes,
        bf16* __restrict__ h0a, bf16* __restrict__ h0b,
        bf16* __restrict__ h1a, bf16* __restrict__ h1b,
        bf16* __restrict__ h2all, unsigned* __restrict__ slots) {
    __shared__ __align__(16) bf16 lds[2][16][LROW];
    int w = blockIdx.x, tid = threadIdx.x;
    int wave = tid >> 6, lane = tid & 63, l15 = lane & 15, q = lane >> 4;

    if (w < 128) {                       // ================= layer 0
        int mg = w >> 2, bg = w & 3;
        int b = bg * 16 + l15;
        int u = mg * 16 + wave * 4 + q;          // unit this lane owns
        int u0 = mg * 16 + wave * 4;             // first unit of this wave (q=0 lane stores)
        bf16x8 A[16][2];
        {
            const bf16* Ab = W0p + (size_t)(mg * 64 + wave * 16 + l15) * K2 + q * 8;
#pragma unroll
            for (int ks = 0; ks < 16; ks++) {
                A[ks][0] = *(const bf16x8*)(Ab + ks * 32);
                A[ks][1] = *(const bf16x8*)(Ab + 512 + ks * 32);
            }
        }
        f32x4 ctxgv = *(const f32x4*)&ctxg[b * G4 + 4 * u];
        const int* bp0 = bytes + b * 520;
        float c = 0.f;
        for (int s = 0; s <= TT; s++) {
            if (s < TT) {
                int t = s;
                // ---- coop stage h0_prev slab (16 batches x 1024) into LDS
                const bf16* hr = (s & 1) ? h0a : h0b;
                const u64* g64 = (const u64*)(hr + (size_t)(bg * 16) * K2);
#pragma unroll
                for (int i = 0; i < 16; i++) {
                    int cch = tid + i * 256;
                    int br = cch >> 8, off = cch & 255;
                    *(u64*)&lds[0][br][off * 4] =
                        __hip_atomic_load(&g64[br * 256 + off], __ATOMIC_RELAXED,
                                          __HIP_MEMORY_SCOPE_AGENT);
                }
                // ---- Z gather (L2/L3-cached, stays warm: no invalidations)
                int vt[8];
#pragma unroll
                for (int j = 0; j < 8; j++) vt[j] = bp0[t + j];
                f32x4 g = ctxgv;
#pragma unroll
                for (int j = 0; j < 8; j++)
                    g += *(const f32x4*)&Z[((size_t)((vt[j] << 3) + j)) * G4 + 4 * u];
                __syncthreads();
                // ---- MFMA: 16 ks x 3 chains
                f32x4 a0 = {0.f,0.f,0.f,0.f}, a1 = a0, a2 = a0;
#pragma unroll
                for (int ks = 0; ks < 16; ks++) {
                    bf16x8 bhh = *(const bf16x8*)&lds[0][l15][ks * 32 + q * 8];
                    bf16x8 bhl = *(const bf16x8*)&lds[0][l15][512 + ks * 32 + q * 8];
                    a0 = MFMA16(A[ks][0], bhh, a0);
                    a1 = MFMA16(A[ks][0], bhl, a1);
                    a2 = MFMA16(A[ks][1], bhh, a2);
                }
                f32x4 acc = a0 + a1 + a2;
                float gi = acc[0] + g[0], gf = acc[1] + g[1], gg = acc[2] + g[2], go = acc[3] + g[3];
                float cnew = sigmoidf_(gf) * c + sigmoidf_(gi) * tanhf(gg);
                c = cnew;
                float h = sigmoidf_(go) * tanhf(cnew);
                // ---- pack across q-lanes, q==0 stores 2x 8B agent atomics
                unsigned hv = pack32(h);
                unsigned p0 = __shfl(hv, l15);
                unsigned p1 = __shfl(hv, l15 + 16);
                unsigned p2 = __shfl(hv, l15 + 32);
                unsigned p3 = __shfl(hv, l15 + 48);
                if (q == 0) {
                    u64 hhp = (u64)(p0 & 0xFFFFu) | ((u64)(p1 & 0xFFFFu) << 16)
                            | ((u64)(p2 & 0xFFFFu) << 32) | ((u64)(p3 & 0xFFFFu) << 48);
                    u64 hlp = (u64)(p0 >> 16) | ((u64)(p1 >> 16) << 16)
                            | ((u64)(p2 >> 16) << 32) | ((u64)(p3 >> 16) << 48);
                    bf16* hw = ((s & 1) ? h0b : h0a) + (size_t)b * K2;
                    __hip_atomic_store((u64*)&hw[u0], hhp, __ATOMIC_RELAXED, __HIP_MEMORY_SCOPE_AGENT);
                    __hip_atomic_store((u64*)&hw[512 + u0], hlp, __ATOMIC_RELAXED, __HIP_MEMORY_SCOPE_AGENT);
                }
            }
            if (s < TT) grid_barrier(slots, w, tid, (unsigned)(s + 1));
        }
    } else {                             // ================= layer 1
        int v = w - 128;
        int mg = v >> 2, bg = v & 3;
        int b = bg * 16 + l15;
        int u = mg * 16 + wave * 4 + q;
        int u0 = mg * 16 + wave * 4;
        bf16x8 A[2][16][2];
        {
            const bf16* Ab = W1p + (size_t)(mg * 64 + wave * 16 + l15) * (2 * K2) + q * 8;
#pragma unroll
            for (int m = 0; m < 2; m++)
#pragma unroll
                for (int ks = 0; ks < 16; ks++) {
                    A[m][ks][0] = *(const bf16x8*)(Ab + m * 1024 + ks * 32);
                    A[m][ks][1] = *(const bf16x8*)(Ab + m * 1024 + 512 + ks * 32);
                }
        }
        f32x4 bi = *(const f32x4*)&bias1p[4 * u];
        float c = 0.f;
        for (int s = 0; s <= TT; s++) {
            if (s >= 1) {
                int t = s - 1;
                // ---- coop stage h0_cur and h1_prev slabs into LDS
                const bf16* hr0 = (s & 1) ? h0a : h0b;   // h0_t
                const bf16* hr1 = (s & 1) ? h1a : h1b;   // h1_{t-1}
                const u64* g0 = (const u64*)(hr0 + (size_t)(bg * 16) * K2);
                const u64* g1 = (const u64*)(hr1 + (size_t)(bg * 16) * K2);
#pragma unroll
                for (int i = 0; i < 16; i++) {
                    int cch = tid + i * 256;
                    int br = cch >> 8, off = cch & 255;
                    *(u64*)&lds[0][br][off * 4] =
                        __hip_atomic_load(&g0[br * 256 + off], __ATOMIC_RELAXED,
                                          __HIP_MEMORY_SCOPE_AGENT);
                    *(u64*)&lds[1][br][off * 4] =
                        __hip_atomic_load(&g1[br * 256 + off], __ATOMIC_RELAXED,
                                          __HIP_MEMORY_SCOPE_AGENT);
                }
                __syncthreads();
                // ---- MFMA: 2 matrices x 16 ks x 3 chains
                f32x4 a0 = {0.f,0.f,0.f,0.f}, a1 = a0, a2 = a0;
#pragma unroll
                for (int ks = 0; ks < 16; ks++) {
                    bf16x8 b0h = *(const bf16x8*)&lds[0][l15][ks * 32 + q * 8];
                    bf16x8 b0l = *(const bf16x8*)&lds[0][l15][512 + ks * 32 + q * 8];
                    a0 = MFMA16(A[0][ks][0], b0h, a0);
                    a1 = MFMA16(A[0][ks][0], b0l, a1);
                    a2 = MFMA16(A[0][ks][1], b0h, a2);
                    bf16x8 b1h = *(const bf16x8*)&lds[1][l15][ks * 32 + q * 8];
                    bf16x8 b1l = *(const bf16x8*)&lds[1][l15][512 + ks * 32 + q * 8];
                    a0 = MFMA16(A[1][ks][0], b1h, a0);
                    a1 = MFMA16(A[1][ks][0], b1l, a1);
                    a2 = MFMA16(A[1][ks][1], b1h, a2);
                }
                f32x4 acc = a0 + a1 + a2;
                float gi = acc[0] + bi[0], gf = acc[1] + bi[1], gg = acc[2] + bi[2], go = acc[3] + bi[3];
                float cnew = sigmoidf_(gf) * c + sigmoidf_(gi) * tanhf(gg);
                c = cnew;
                float h = sigmoidf_(go) * tanhf(cnew);
                unsigned hv = pack32(h);
                unsigned p0 = __shfl(hv, l15);
                unsigned p1 = __shfl(hv, l15 + 16);
                unsigned p2 = __shfl(hv, l15 + 32);
                unsigned p3 = __shfl(hv, l15 + 48);
                if (q == 0) {
                    u64 hhp = (u64)(p0 & 0xFFFFu) | ((u64)(p1 & 0xFFFFu) << 16)
                            | ((u64)(p2 & 0xFFFFu) << 32) | ((u64)(p3 & 0xFFFFu) << 48);
                    u64 hlp = (u64)(p0 >> 16) | ((u64)(p1 >> 16) << 16)
                            | ((u64)(p2 >> 16) << 32) | ((u64)(p3 >> 16) << 48);
                    bf16* hw = ((s & 1) ? h1b : h1a) + (size_t)b * K2;
                    __hip_atomic_store((u64*)&hw[u0], hhp, __ATOMIC_RELAXED, __HIP_MEMORY_SCOPE_AGENT);
                    __hip_atomic_store((u64*)&hw[512 + u0], hlp, __ATOMIC_RELAXED, __HIP_MEMORY_SCOPE_AGENT);
                    bf16* h2 = h2all + ((size_t)(t * 64 + b)) * K2;   // normal stores: flushed at kernel end
                    *(u64*)&h2[u0] = hhp;
                    *(u64*)&h2[512 + u0] = hlp;
                }
            }
            if (s < TT) grid_barrier(slots, w, tid, (unsigned)(s + 1));
        }
    }
}

// ---------------------------------------------------------------------------
// Phase C: logits = Woutp (triple K3) . h2 (2-plane K2, k>=1024 -> k-1024)
// ---------------------------------------------------------------------------
__global__ __launch_bounds__(256, 2) void gemm_out(const bf16* __restrict__ Wp,
                                                   const bf16* __restrict__ H2,
                                                   const float* __restrict__ bout,
                                                   float* __restrict__ out) {
    __shared__ bf16 As[128 * 32];
    __shared__ bf16 Bs[128 * 32];
    int mt = blockIdx.x, nt = blockIdx.y;
    int tid = threadIdx.x, wave = tid >> 6, lane = tid & 63;
    int l15 = lane & 15, q = lane >> 4;
    int msub = (wave & 1) * 64, nsub = (wave >> 1) * 64;
    f32x4 acc[4][4] = {};
    const bf16* Abase = Wp + (size_t)(mt * 128) * K3;
    const bf16* Bbase = H2 + (size_t)(nt * 128) * K2;
    for (int ks = 0; ks < K3 / 32; ks++) {
        int k0 = ks * 32;
        int kb = (k0 < 1024) ? k0 : (k0 - 1024);
        __syncthreads();
#pragma unroll
        for (int rnd = 0; rnd < 2; rnd++) {
            int cch = tid + rnd * 256;
            int rr = cch >> 2, seg = cch & 3;
            *(int4*)&As[cch * 8] = *(const int4*)&Abase[(size_t)rr * K3 + k0 + seg * 8];
            *(int4*)&Bs[cch * 8] = *(const int4*)&Bbase[(size_t)rr * K2 + kb + seg * 8];
        }
        __syncthreads();
        bf16x8 af[4], bf_[4];
#pragma unroll
        for (int i = 0; i < 4; i++) af[i]  = *(const bf16x8*)&As[(msub + i * 16 + l15) * 32 + q * 8];
#pragma unroll
        for (int j = 0; j < 4; j++) bf_[j] = *(const bf16x8*)&Bs[(nsub + j * 16 + l15) * 32 + q * 8];
#pragma unroll
        for (int i = 0; i < 4; i++)
#pragma unroll
            for (int j = 0; j < 4; j++)
                acc[i][j] = MFMA16(af[i], bf_[j], acc[i][j]);
    }
#pragma unroll
    for (int i = 0; i < 4; i++) {
        int m = mt * 128 + msub + i * 16 + q * 4;     // vocab row
        f32x4 bi = *(const f32x4*)&bout[m];
#pragma unroll
        for (int j = 0; j < 4; j++) {
            int n = nt * 128 + nsub + j * 16 + l15;   // t*64+b
            int t = n >> 6, b = n & 63;
            f32x4 v = acc[i][j] + bi;
            *(f32x4*)&out[((size_t)(b * 512 + t)) * 256 + m] = v;
        }
    }
}

// ---------------------------------------------------------------------------
extern "C" void kernel_launch(void* const* d_in, const int* in_sizes, int n_in,
                              void* d_out, int out_size, void* d_ws, size_t ws_size,
                              hipStream_t stream) {
    const float* ecc   = (const float*)d_in[0];
    const int*   npc   = (const int*)d_in[1];
    const float* npn   = (const float*)d_in[2];
    const int*   payld = (const int*)d_in[3];
    const float* cat0  = (const float*)d_in[4];
    const float* cat1  = (const float*)d_in[5];
    const float* cat2  = (const float*)d_in[6];
    const float* bemb  = (const float*)d_in[7];
    const float* Wih0  = (const float*)d_in[8];
    const float* Whh0  = (const float*)d_in[9];
    const float* bih0  = (const float*)d_in[10];
    const float* bhh0  = (const float*)d_in[11];
    const float* Wih1  = (const float*)d_in[12];
    const float* Whh1  = (const float*)d_in[13];
    const float* bih1  = (const float*)d_in[14];
    const float* bhh1  = (const float*)d_in[15];
    const float* Wout  = (const float*)d_in[16];
    const float* bout  = (const float*)d_in[17];
    float* out = (float*)d_out;

    char* ws = (char*)d_ws;
    size_t off = 0;
    auto alloc = [&](size_t bytes) -> void* {
        void* p = ws + off;
        off = (off + bytes + 255) & ~(size_t)255;
        return p;
    };

    // zeroed state block (contiguous)
    size_t zoff = off;
    bf16* h0a = (bf16*)alloc((size_t)BB * K2 * 2);
    bf16* h0b = (bf16*)alloc((size_t)BB * K2 * 2);
    bf16* h1a = (bf16*)alloc((size_t)BB * K2 * 2);
    bf16* h1b = (bf16*)alloc((size_t)BB * K2 * 2);
    unsigned* slots = (unsigned*)alloc(NWG * 4);
    size_t zbytes = off - zoff;

    bf16* W0p    = (bf16*)alloc((size_t)G4 * K2 * 2);
    bf16* W1p    = (bf16*)alloc((size_t)G4 * 2 * K2 * 2);
    bf16* Woutp  = (bf16*)alloc((size_t)256 * K3 * 2);
    float* bias1p = (float*)alloc((size_t)G4 * 4);
    float* Z      = (float*)alloc((size_t)260 * 8 * G4 * 4);
    float* ctxg   = (float*)alloc((size_t)BB * G4 * 4);
    int*   bytesb = (int*)alloc((size_t)BB * 520 * 4);
    bf16* h2all   = (bf16*)alloc((size_t)NROW * K2 * 2);

    if (ws_size < off) return;   // out stays poisoned -> signals ws too small

    hipMemsetAsync(ws + zoff, 0, zbytes, stream);

    pad_bytes <<<BB, 256, 0, stream>>>(payld, bytesb);
    build_Z   <<<dim3(260, 8), 256, 0, stream>>>(Wih0, bemb, Z);
    build_ctxg<<<BB, 256, 0, stream>>>(ecc, npc, npn, cat0, cat1, cat2, bih0, bhh0, Wih0, ctxg);
    conv_w0   <<<G4, 256, 0, stream>>>(Whh0, W0p);
    conv_w1   <<<G4, 256, 0, stream>>>(Wih1, Whh1, W1p);
    conv_wout <<<256, 256, 0, stream>>>(Wout, Woutp);
    conv_bias <<<8, 256, 0, stream>>>(bih1, bhh1, bias1p);

    lstm_persist<<<NWG, 256, 0, stream>>>(W0p, W1p, bias1p, ctxg, Z, bytesb,
                                          h0a, h0b, h1a, h1b, h2all, slots);

    gemm_out<<<dim3(2, 256), 256, 0, stream>>>(Woutp, h2all, bout, out);
}

// Round 6
// 4597.331 us; speedup vs baseline: 4.6041x; 1.4961x over previous
//
#include <hip/hip_runtime.h>
#include <hip/hip_bf16.h>
#include <math.h>

typedef __bf16 bf16;
typedef __bf16 bf16x8 __attribute__((ext_vector_type(8)));
typedef float  f32x4  __attribute__((ext_vector_type(4)));
typedef unsigned long long u64;

#define MFMA16(a, b, c) __builtin_amdgcn_mfma_f32_16x16x32_bf16((a), (b), (c), 0, 0, 0)

// Problem constants
#define BB 64
#define TT 512
#define HH 512
#define G4 2048      // 4*HH gate rows, permuted row' = 4*u + g
#define NROW 32768   // BB*TT, row index r = t*64 + b
#define K2 1024      // dedup 2-plane width: [hi|lo] weights, [hh|hl] activations
#define K3 1536      // logical triple K for gemm_out (A = [hi|hi|lo], B mapped)
#define NWG 256
#define LROW 1032    // LDS slab row stride in bf16 (516 dwords; stride-4 banks => conflict-free b128)

#define AGLD(p) __hip_atomic_load((p), __ATOMIC_RELAXED, __HIP_MEMORY_SCOPE_AGENT)
#define AGST(p, v) __hip_atomic_store((p), (v), __ATOMIC_RELAXED, __HIP_MEMORY_SCOPE_AGENT)

__device__ __forceinline__ float sigmoidf_(float x) { return 1.0f / (1.0f + expf(-x)); }

__device__ __forceinline__ unsigned pack32(float h) {
    bf16 hh = (bf16)h;
    bf16 hl = (bf16)(h - (float)hh);
    unsigned short uh = __builtin_bit_cast(unsigned short, hh);
    unsigned short ul = __builtin_bit_cast(unsigned short, hl);
    return (unsigned)uh | ((unsigned)ul << 16);
}

// ---------------------------------------------------------------------------
// Setup kernels (unchanged)
// ---------------------------------------------------------------------------
__global__ void pad_bytes(const int* __restrict__ payload, int* __restrict__ bytes) {
    int b = blockIdx.x;
    for (int p = threadIdx.x; p < 520; p += blockDim.x)
        bytes[b * 520 + p] = (p < 7) ? 256 : ((p == 7) ? 257 : payload[b * 512 + p - 8]);
}

__global__ void build_Z(const float* __restrict__ Wih0, const float* __restrict__ bemb,
                        float* __restrict__ Z) {
    int v = blockIdx.x, j = blockIdx.y;
    __shared__ float e[32];
    if (threadIdx.x < 32) e[threadIdx.x] = bemb[v * 32 + threadIdx.x];
    __syncthreads();
#pragma unroll
    for (int i = 0; i < 8; i++) {
        int mp = threadIdx.x + i * 256;
        int u = mp >> 2, g = mp & 3;
        const float* wr = Wih0 + (size_t)(g * 512 + u) * 1048 + 792 + j * 32;
        float sum = 0.f;
#pragma unroll
        for (int kk = 0; kk < 32; kk++) sum += wr[kk] * e[kk];
        Z[((size_t)(v * 8 + j)) * G4 + mp] = sum;
    }
}

__global__ void build_ctxg(const float* __restrict__ ecc, const int* __restrict__ npc,
                           const float* __restrict__ npn,
                           const float* __restrict__ cat0, const float* __restrict__ cat1,
                           const float* __restrict__ cat2,
                           const float* __restrict__ bih0, const float* __restrict__ bhh0,
                           const float* __restrict__ Wih0, float* __restrict__ ctxg) {
    int b = blockIdx.x;
    __shared__ float cs[792];
    for (int k = threadIdx.x; k < 792; k += blockDim.x) {
        float v;
        if (k < 512)       v = ecc[b * 512 + k];
        else if (k < 562)  v = cat0[npc[b * 3 + 0] * 50 + (k - 512)];
        else if (k < 626)  v = cat1[npc[b * 3 + 1] * 64 + (k - 562)];
        else if (k < 776)  v = cat2[npc[b * 3 + 2] * 150 + (k - 626)];
        else               v = npn[b * 16 + (k - 776)];
        cs[k] = v;
    }
    __syncthreads();
#pragma unroll
    for (int i = 0; i < 8; i++) {
        int mp = threadIdx.x + i * 256;
        int u = mp >> 2, g = mp & 3;
        int orow = g * 512 + u;
        const float* wr = Wih0 + (size_t)orow * 1048;
        float sum = bih0[orow] + bhh0[orow];
        for (int k = 0; k < 792; k++) sum += wr[k] * cs[k];
        ctxg[b * G4 + mp] = sum;
    }
}

__global__ void conv_w0(const float* __restrict__ Whh0, bf16* __restrict__ W0p) {
    int rp = blockIdx.x; int u = rp >> 2, g = rp & 3;
    const float* src = Whh0 + (size_t)(g * 512 + u) * 512;
    bf16* dst = W0p + (size_t)rp * K2;
    for (int k = threadIdx.x; k < 512; k += blockDim.x) {
        float w = src[k]; bf16 hi = (bf16)w; bf16 lo = (bf16)(w - (float)hi);
        dst[k] = hi; dst[512 + k] = lo;
    }
}
__global__ void conv_w1(const float* __restrict__ Wih1, const float* __restrict__ Whh1,
                        bf16* __restrict__ W1p) {
    int rp = blockIdx.x; int u = rp >> 2, g = rp & 3;
    const float* s0 = Wih1 + (size_t)(g * 512 + u) * 512;
    const float* s1 = Whh1 + (size_t)(g * 512 + u) * 512;
    bf16* dst = W1p + (size_t)rp * (2 * K2);
    for (int k = threadIdx.x; k < 512; k += blockDim.x) {
        float w0 = s0[k]; bf16 h0 = (bf16)w0; bf16 l0 = (bf16)(w0 - (float)h0);
        dst[k] = h0; dst[512 + k] = l0;
        float w1 = s1[k]; bf16 h1 = (bf16)w1; bf16 l1 = (bf16)(w1 - (float)h1);
        dst[1024 + k] = h1; dst[1536 + k] = l1;
    }
}
__global__ void conv_wout(const float* __restrict__ Wout, bf16* __restrict__ Woutp) {
    int r = blockIdx.x;
    const float* src = Wout + (size_t)r * 512;
    bf16* dst = Woutp + (size_t)r * K3;            // triple [hi|hi|lo]
    for (int k = threadIdx.x; k < 512; k += blockDim.x) {
        float w = src[k]; bf16 hi = (bf16)w; bf16 lo = (bf16)(w - (float)hi);
        dst[k] = hi; dst[512 + k] = hi; dst[1024 + k] = lo;
    }
}
__global__ void conv_bias(const float* __restrict__ bih1, const float* __restrict__ bhh1,
                          float* __restrict__ bias1p) {
    int rp = blockIdx.x * blockDim.x + threadIdx.x;
    if (rp >= G4) return;
    int u = rp >> 2, g = rp & 3; int orow = g * 512 + u;
    bias1p[rp] = bih1[orow] + bhh1[orow];
}

// ---------------------------------------------------------------------------
// Per-bg sub-barrier: 64 wgs share a bg (32 L0: w=4*mg+bg; 32 L1: w=128+4*mg+bg).
// Only wave 0 polls (lane p polls slot p of the group); others wait at the
// second __syncthreads. No cache ops anywhere (agent atomics are read/write-
// through), so L2 stays warm for Z/weights.
// ---------------------------------------------------------------------------
__device__ __forceinline__ void group_barrier(unsigned* slots, int myslot, int bg,
                                              int tid, unsigned s1) {
    __syncthreads();                 // all waves' h atomic stores vmcnt-drained
    __threadfence_block();
    if (tid == 0) AGST(&slots[myslot], s1);
    if (tid < 64) {
        int p = tid;
        int wpoll = (p < 32) ? (p * 4 + bg) : (128 + (p - 32) * 4 + bg);
        while (AGLD(&slots[wpoll]) < s1) __builtin_amdgcn_s_sleep(1);
    }
    __threadfence_block();
    __syncthreads();
}

// ---------------------------------------------------------------------------
// Persistent LSTM. 256 wgs x 256 thr, 1 wg/CU.
//  w < 128 : layer0, mg = w>>2, bg = w&3   (rows mg*64..+64, batches bg*16..+16)
//  w >= 128: layer1, same decomposition.
// Two-phase staging: all slab atomic loads -> regs, then b128 LDS writes.
// ---------------------------------------------------------------------------
__global__ __launch_bounds__(256, 1) void lstm_persist(
        const bf16* __restrict__ W0p, const bf16* __restrict__ W1p,
        const float* __restrict__ bias1p, const float* __restrict__ ctxg,
        const float* __restrict__ Z, const int* __restrict__ bytes,
        bf16* __restrict__ h0a, bf16* __restrict__ h0b,
        bf16* __restrict__ h1a, bf16* __restrict__ h1b,
        bf16* __restrict__ h2all, unsigned* __restrict__ slots) {
    __shared__ __align__(16) bf16 lds[2][16][LROW];
    int w = blockIdx.x, tid = threadIdx.x;
    int wave = tid >> 6, lane = tid & 63, l15 = lane & 15, q = lane >> 4;

    if (w < 128) {                       // ================= layer 0
        int mg = w >> 2, bg = w & 3;
        int b = bg * 16 + l15;
        int u = mg * 16 + wave * 4 + q;
        int u0 = mg * 16 + wave * 4;
        bf16x8 A[16][2];
        {
            const bf16* Ab = W0p + (size_t)(mg * 64 + wave * 16 + l15) * K2 + q * 8;
#pragma unroll
            for (int ks = 0; ks < 16; ks++) {
                A[ks][0] = *(const bf16x8*)(Ab + ks * 32);
                A[ks][1] = *(const bf16x8*)(Ab + 512 + ks * 32);
            }
        }
        f32x4 ctxgv = *(const f32x4*)&ctxg[b * G4 + 4 * u];
        const int* bp0 = bytes + b * 520;
        float c = 0.f;
        for (int s = 0; s <= TT; s++) {
            if (s < TT) {
                int t = s;
                // ---- phase 1: issue ALL slab loads (pipelined IC round-trips)
                const bf16* hr = (s & 1) ? h0a : h0b;
                const u64* g64 = (const u64*)(hr + (size_t)(bg * 16) * K2);
                u64 tmp[16];
#pragma unroll
                for (int i = 0; i < 8; i++) {
                    int cch = tid + i * 256;                // 16B chunk id, 0..2047
                    tmp[2 * i]     = AGLD(&g64[2 * cch]);
                    tmp[2 * i + 1] = AGLD(&g64[2 * cch + 1]);
                }
                // ---- Z gather (normal cached loads, overlap with IC loads)
                int vt[8];
#pragma unroll
                for (int j = 0; j < 8; j++) vt[j] = bp0[t + j];
                f32x4 g = ctxgv;
#pragma unroll
                for (int j = 0; j < 8; j++)
                    g += *(const f32x4*)&Z[((size_t)((vt[j] << 3) + j)) * G4 + 4 * u];
                // ---- phase 2: LDS writes (b128, conflict-free stride)
#pragma unroll
                for (int i = 0; i < 8; i++) {
                    int cch = tid + i * 256;
                    int br = cch >> 7, off = cch & 127;
                    u64 pr[2] = { tmp[2 * i], tmp[2 * i + 1] };
                    *(int4*)&lds[0][br][off * 8] = *(const int4*)pr;
                }
                __syncthreads();
                // ---- MFMA: 16 ks x 3 chains
                f32x4 a0 = {0.f,0.f,0.f,0.f}, a1 = a0, a2 = a0;
#pragma unroll
                for (int ks = 0; ks < 16; ks++) {
                    bf16x8 bhh = *(const bf16x8*)&lds[0][l15][ks * 32 + q * 8];
                    bf16x8 bhl = *(const bf16x8*)&lds[0][l15][512 + ks * 32 + q * 8];
                    a0 = MFMA16(A[ks][0], bhh, a0);
                    a1 = MFMA16(A[ks][0], bhl, a1);
                    a2 = MFMA16(A[ks][1], bhh, a2);
                }
                f32x4 acc = a0 + a1 + a2;
                float gi = acc[0] + g[0], gf = acc[1] + g[1], gg = acc[2] + g[2], go = acc[3] + g[3];
                float cnew = sigmoidf_(gf) * c + sigmoidf_(gi) * tanhf(gg);
                c = cnew;
                float h = sigmoidf_(go) * tanhf(cnew);
                unsigned hv = pack32(h);
                unsigned p0 = __shfl(hv, l15);
                unsigned p1 = __shfl(hv, l15 + 16);
                unsigned p2 = __shfl(hv, l15 + 32);
                unsigned p3 = __shfl(hv, l15 + 48);
                if (q == 0) {
                    u64 hhp = (u64)(p0 & 0xFFFFu) | ((u64)(p1 & 0xFFFFu) << 16)
                            | ((u64)(p2 & 0xFFFFu) << 32) | ((u64)(p3 & 0xFFFFu) << 48);
                    u64 hlp = (u64)(p0 >> 16) | ((u64)(p1 >> 16) << 16)
                            | ((u64)(p2 >> 16) << 32) | ((u64)(p3 >> 16) << 48);
                    bf16* hw = ((s & 1) ? h0b : h0a) + (size_t)b * K2;
                    AGST((u64*)&hw[u0], hhp);
                    AGST((u64*)&hw[512 + u0], hlp);
                }
            }
            if (s < TT) group_barrier(slots, w, bg, tid, (unsigned)(s + 1));
        }
    } else {                             // ================= layer 1
        int v = w - 128;
        int mg = v >> 2, bg = v & 3;
        int b = bg * 16 + l15;
        int u = mg * 16 + wave * 4 + q;
        int u0 = mg * 16 + wave * 4;
        bf16x8 A[2][16][2];
        {
            const bf16* Ab = W1p + (size_t)(mg * 64 + wave * 16 + l15) * (2 * K2) + q * 8;
#pragma unroll
            for (int m = 0; m < 2; m++)
#pragma unroll
                for (int ks = 0; ks < 16; ks++) {
                    A[m][ks][0] = *(const bf16x8*)(Ab + m * 1024 + ks * 32);
                    A[m][ks][1] = *(const bf16x8*)(Ab + m * 1024 + 512 + ks * 32);
                }
        }
        f32x4 bi = *(const f32x4*)&bias1p[4 * u];
        float c = 0.f;
        for (int s = 0; s <= TT; s++) {
            if (s >= 1) {
                int t = s - 1;
                const bf16* hr0 = (s & 1) ? h0a : h0b;   // h0_t
                const bf16* hr1 = (s & 1) ? h1a : h1b;   // h1_{t-1}
                const u64* g0 = (const u64*)(hr0 + (size_t)(bg * 16) * K2);
                const u64* g1 = (const u64*)(hr1 + (size_t)(bg * 16) * K2);
                u64 tmp[32];
#pragma unroll
                for (int i = 0; i < 8; i++) {
                    int cch = tid + i * 256;
                    tmp[2 * i]      = AGLD(&g0[2 * cch]);
                    tmp[2 * i + 1]  = AGLD(&g0[2 * cch + 1]);
                    tmp[16 + 2 * i] = AGLD(&g1[2 * cch]);
                    tmp[17 + 2 * i] = AGLD(&g1[2 * cch + 1]);
                }
#pragma unroll
                for (int i = 0; i < 8; i++) {
                    int cch = tid + i * 256;
                    int br = cch >> 7, off = cch & 127;
                    u64 p0_[2] = { tmp[2 * i], tmp[2 * i + 1] };
                    u64 p1_[2] = { tmp[16 + 2 * i], tmp[17 + 2 * i] };
                    *(int4*)&lds[0][br][off * 8] = *(const int4*)p0_;
                    *(int4*)&lds[1][br][off * 8] = *(const int4*)p1_;
                }
                __syncthreads();
                f32x4 a0 = {0.f,0.f,0.f,0.f}, a1 = a0, a2 = a0;
#pragma unroll
                for (int ks = 0; ks < 16; ks++) {
                    bf16x8 b0h = *(const bf16x8*)&lds[0][l15][ks * 32 + q * 8];
                    bf16x8 b0l = *(const bf16x8*)&lds[0][l15][512 + ks * 32 + q * 8];
                    a0 = MFMA16(A[0][ks][0], b0h, a0);
                    a1 = MFMA16(A[0][ks][0], b0l, a1);
                    a2 = MFMA16(A[0][ks][1], b0h, a2);
                    bf16x8 b1h = *(const bf16x8*)&lds[1][l15][ks * 32 + q * 8];
                    bf16x8 b1l = *(const bf16x8*)&lds[1][l15][512 + ks * 32 + q * 8];
                    a0 = MFMA16(A[1][ks][0], b1h, a0);
                    a1 = MFMA16(A[1][ks][0], b1l, a1);
                    a2 = MFMA16(A[1][ks][1], b1h, a2);
                }
                f32x4 acc = a0 + a1 + a2;
                float gi = acc[0] + bi[0], gf = acc[1] + bi[1], gg = acc[2] + bi[2], go = acc[3] + bi[3];
                float cnew = sigmoidf_(gf) * c + sigmoidf_(gi) * tanhf(gg);
                c = cnew;
                float h = sigmoidf_(go) * tanhf(cnew);
                unsigned hv = pack32(h);
                unsigned p0 = __shfl(hv, l15);
                unsigned p1 = __shfl(hv, l15 + 16);
                unsigned p2 = __shfl(hv, l15 + 32);
                unsigned p3 = __shfl(hv, l15 + 48);
                if (q == 0) {
                    u64 hhp = (u64)(p0 & 0xFFFFu) | ((u64)(p1 & 0xFFFFu) << 16)
                            | ((u64)(p2 & 0xFFFFu) << 32) | ((u64)(p3 & 0xFFFFu) << 48);
                    u64 hlp = (u64)(p0 >> 16) | ((u64)(p1 >> 16) << 16)
                            | ((u64)(p2 >> 16) << 32) | ((u64)(p3 >> 16) << 48);
                    bf16* hw = ((s & 1) ? h1b : h1a) + (size_t)b * K2;
                    AGST((u64*)&hw[u0], hhp);
                    AGST((u64*)&hw[512 + u0], hlp);
                    bf16* h2 = h2all + ((size_t)(t * 64 + b)) * K2;   // plain stores
                    *(u64*)&h2[u0] = hhp;
                    *(u64*)&h2[512 + u0] = hlp;
                }
            }
            if (s < TT) group_barrier(slots, w, bg, tid, (unsigned)(s + 1));
        }
    }
}

// ---------------------------------------------------------------------------
// Phase C: logits = Woutp (triple K3) . h2 (2-plane K2, k>=1024 -> k-1024)
// ---------------------------------------------------------------------------
__global__ __launch_bounds__(256, 2) void gemm_out(const bf16* __restrict__ Wp,
                                                   const bf16* __restrict__ H2,
                                                   const float* __restrict__ bout,
                                                   float* __restrict__ out) {
    __shared__ bf16 As[128 * 32];
    __shared__ bf16 Bs[128 * 32];
    int mt = blockIdx.x, nt = blockIdx.y;
    int tid = threadIdx.x, wave = tid >> 6, lane = tid & 63;
    int l15 = lane & 15, q = lane >> 4;
    int msub = (wave & 1) * 64, nsub = (wave >> 1) * 64;
    f32x4 acc[4][4] = {};
    const bf16* Abase = Wp + (size_t)(mt * 128) * K3;
    const bf16* Bbase = H2 + (size_t)(nt * 128) * K2;
    for (int ks = 0; ks < K3 / 32; ks++) {
        int k0 = ks * 32;
        int kb = (k0 < 1024) ? k0 : (k0 - 1024);
        __syncthreads();
#pragma unroll
        for (int rnd = 0; rnd < 2; rnd++) {
            int cch = tid + rnd * 256;
            int rr = cch >> 2, seg = cch & 3;
            *(int4*)&As[cch * 8] = *(const int4*)&Abase[(size_t)rr * K3 + k0 + seg * 8];
            *(int4*)&Bs[cch * 8] = *(const int4*)&Bbase[(size_t)rr * K2 + kb + seg * 8];
        }
        __syncthreads();
        bf16x8 af[4], bf_[4];
#pragma unroll
        for (int i = 0; i < 4; i++) af[i]  = *(const bf16x8*)&As[(msub + i * 16 + l15) * 32 + q * 8];
#pragma unroll
        for (int j = 0; j < 4; j++) bf_[j] = *(const bf16x8*)&Bs[(nsub + j * 16 + l15) * 32 + q * 8];
#pragma unroll
        for (int i = 0; i < 4; i++)
#pragma unroll
            for (int j = 0; j < 4; j++)
                acc[i][j] = MFMA16(af[i], bf_[j], acc[i][j]);
    }
#pragma unroll
    for (int i = 0; i < 4; i++) {
        int m = mt * 128 + msub + i * 16 + q * 4;     // vocab row
        f32x4 bi = *(const f32x4*)&bout[m];
#pragma unroll
        for (int j = 0; j < 4; j++) {
            int n = nt * 128 + nsub + j * 16 + l15;   // t*64+b
            int t = n >> 6, b = n & 63;
            f32x4 v = acc[i][j] + bi;
            *(f32x4*)&out[((size_t)(b * 512 + t)) * 256 + m] = v;
        }
    }
}

// ---------------------------------------------------------------------------
extern "C" void kernel_launch(void* const* d_in, const int* in_sizes, int n_in,
                              void* d_out, int out_size, void* d_ws, size_t ws_size,
                              hipStream_t stream) {
    const float* ecc   = (const float*)d_in[0];
    const int*   npc   = (const int*)d_in[1];
    const float* npn   = (const float*)d_in[2];
    const int*   payld = (const int*)d_in[3];
    const float* cat0  = (const float*)d_in[4];
    const float* cat1  = (const float*)d_in[5];
    const float* cat2  = (const float*)d_in[6];
    const float* bemb  = (const float*)d_in[7];
    const float* Wih0  = (const float*)d_in[8];
    const float* Whh0  = (const float*)d_in[9];
    const float* bih0  = (const float*)d_in[10];
    const float* bhh0  = (const float*)d_in[11];
    const float* Wih1  = (const float*)d_in[12];
    const float* Whh1  = (const float*)d_in[13];
    const float* bih1  = (const float*)d_in[14];
    const float* bhh1  = (const float*)d_in[15];
    const float* Wout  = (const float*)d_in[16];
    const float* bout  = (const float*)d_in[17];
    float* out = (float*)d_out;

    char* ws = (char*)d_ws;
    size_t off = 0;
    auto alloc = [&](size_t bytes) -> void* {
        void* p = ws + off;
        off = (off + bytes + 255) & ~(size_t)255;
        return p;
    };

    // zeroed state block (contiguous)
    size_t zoff = off;
    bf16* h0a = (bf16*)alloc((size_t)BB * K2 * 2);
    bf16* h0b = (bf16*)alloc((size_t)BB * K2 * 2);
    bf16* h1a = (bf16*)alloc((size_t)BB * K2 * 2);
    bf16* h1b = (bf16*)alloc((size_t)BB * K2 * 2);
    unsigned* slots = (unsigned*)alloc(NWG * 4);
    size_t zbytes = off - zoff;

    bf16* W0p    = (bf16*)alloc((size_t)G4 * K2 * 2);
    bf16* W1p    = (bf16*)alloc((size_t)G4 * 2 * K2 * 2);
    bf16* Woutp  = (bf16*)alloc((size_t)256 * K3 * 2);
    float* bias1p = (float*)alloc((size_t)G4 * 4);
    float* Z      = (float*)alloc((size_t)260 * 8 * G4 * 4);
    float* ctxg   = (float*)alloc((size_t)BB * G4 * 4);
    int*   bytesb = (int*)alloc((size_t)BB * 520 * 4);
    bf16* h2all   = (bf16*)alloc((size_t)NROW * K2 * 2);

    if (ws_size < off) return;   // out stays poisoned -> signals ws too small

    hipMemsetAsync(ws + zoff, 0, zbytes, stream);

    pad_bytes <<<BB, 256, 0, stream>>>(payld, bytesb);
    build_Z   <<<dim3(260, 8), 256, 0, stream>>>(Wih0, bemb, Z);
    build_ctxg<<<BB, 256, 0, stream>>>(ecc, npc, npn, cat0, cat1, cat2, bih0, bhh0, Wih0, ctxg);
    conv_w0   <<<G4, 256, 0, stream>>>(Whh0, W0p);
    conv_w1   <<<G4, 256, 0, stream>>>(Wih1, Whh1, W1p);
    conv_wout <<<256, 256, 0, stream>>>(Wout, Woutp);
    conv_bias <<<8, 256, 0, stream>>>(bih1, bhh1, bias1p);

    lstm_persist<<<NWG, 256, 0, stream>>>(W0p, W1p, bias1p, ctxg, Z, bytesb,
                                          h0a, h0b, h1a, h1b, h2all, slots);

    gemm_out<<<dim3(2, 256), 256, 0, stream>>>(Woutp, h2all, bout, out);
}